// Round 9
// baseline (17.905 us; speedup 1.0000x reference)
//
#include <hip/hip_runtime.h>
#include <math.h>

#define B_SZ 256
#define U_SZ 4096
#define V_SZ 80
#define H_SZ 1024
#define K_SZ 10
#define CPRE 64   // c rows held in registers then LDS per batch
#define CPRE_F4 (CPRE * V_SZ / 4)   // 1280 float4

// d_out layout (floats, concatenated in return order):
//   [0, B*V)                       w            (256*80   = 20480)
//   [B*V, B*V + B*K)               new_kappa    (256*10   = 2560)
//   [B*V + B*K, ... + B*(U+1))     phi_term     (256*4097 = 1048832)
#define OUT_W_OFF      0
#define OUT_NK_OFF     (B_SZ * V_SZ)
#define OUT_PT_OFF     (B_SZ * V_SZ + B_SZ * K_SZ)

// One block (1024 threads = 16 waves) per batch. Barrier chain A-B-D-E,
// but ALL global stores are deferred to after E, so B/D/E never drain vmem
// (the s_waitcnt vmcnt(0) before each s_barrier is dynamically free).
//   entry:  c rows (1280 float4) -> regs, params -> regs, zero phi_s[64]
//   pre-A:  lin = x @ W.T (16 waves, float4, direct from global)
//   A ----  (the single real vmem drain: entry loads)
//   creg -> LDS ; wave-0: scalars -> LDS + analytic cutoff (< e^-60 beyond)
//   B ----  (LDS-only)
//   phase 3: phi(u) for u=tid<=ucut -> phi_s (LDS) + s kept in reg
//   D ----  (LDS-only)
//   phase 4: w partials from LDS c rows (cold tail: recompute phi inline)
//   E ----  (LDS-only)
//   post-E: store w, new_kappa, pt[0..ucut], zero-fill pt[(ucut,U]]
//           (all retire at endpgm, never drained by a barrier)
__global__ __launch_bounds__(1024) void fused_softwindow(
        const float* __restrict__ x,
        const float* __restrict__ c,
        const float* __restrict__ kappa,
        const float* __restrict__ W,
        const float* __restrict__ bias,
        const int*   __restrict__ lens,
        float* __restrict__ out) {
    __shared__ float cs[CPRE * V_SZ];          // 20 KB
    __shared__ float lin_s[32];
    __shared__ float a_s[K_SZ], nb_s[K_SZ], nk_s[K_SZ];
    __shared__ float phi_s[CPRE];              // 64 floats (phase 4 main loop)
    __shared__ float wpart[12][V_SZ];
    __shared__ int   ucut_sh;

    const int b    = blockIdx.x;
    const int tid  = threadIdx.x;
    const int wave = tid >> 6;
    const int lane = tid & 63;
    const int len  = lens[b];

    const float*  cb  = c + (size_t)b * U_SZ * V_SZ;
    const float4* cb4 = (const float4*)cb;

    // entry: c prefetch into registers — exactly CPRE_F4 = 1280 float4
    float4 creg0, creg1;
    creg0 = cb4[tid];                                   // tid < 1024
    if (tid < CPRE_F4 - 1024) creg1 = cb4[tid + 1024];  // 256 threads

    // entry: kappa/bias prefetch (used by wave 0 in phase 2)
    float kap = 0.f, bs0 = 0.f, bs1 = 0.f, bs2 = 0.f;
    if (tid < K_SZ) {
        kap = kappa[b * K_SZ + tid];
        bs0 = bias[tid];
        bs1 = bias[K_SZ + tid];
        bs2 = bias[2 * K_SZ + tid];
    }

    // zero phi_s (64 entries; cross-thread reads only after barrier D)
    if (tid < CPRE) phi_s[tid] = 0.f;

    // phase 1: lin = x @ W.T, x and W direct from global
    {
        const float4* xb4 = (const float4*)(x + (size_t)b * H_SZ);
        float4 xv[4];
        #pragma unroll
        for (int j = 0; j < 4; ++j) xv[j] = xb4[lane + 64 * j];
        for (int k = wave; k < 3 * K_SZ; k += 16) {
            const float4* Wk4 = (const float4*)(W + (size_t)k * H_SZ);
            float p = 0.f;
            #pragma unroll
            for (int j = 0; j < 4; ++j) {
                float4 wv = Wk4[lane + 64 * j];
                p += wv.x * xv[j].x + wv.y * xv[j].y +
                     wv.z * xv[j].z + wv.w * xv[j].w;
            }
            #pragma unroll
            for (int off = 32; off > 0; off >>= 1) p += __shfl_down(p, off);
            if (lane == 0) lin_s[k] = p;
        }
    }

    __syncthreads();  // A: lin_s ready; entry loads drained (the only real drain)

    // creg -> LDS layout bounce (read by phase 4 after barrier D)
    {
        float4* cs4 = (float4*)cs;
        cs4[tid] = creg0;
        if (tid < CPRE_F4 - 1024) cs4[tid + 1024] = creg1;
    }

    // phase 2: wave-0 scalars + in-wave cutoff reduce; nk kept in REG for
    // post-E store (no global store before a barrier)
    float nk_keep = 0.f;
    if (wave == 0) {
        float cut = 0.f;
        if (lane < K_SZ) {
            float ah = lin_s[lane]            + bs0;
            float bh = lin_s[K_SZ + lane]     + bs1;
            float kh = lin_s[2 * K_SZ + lane] + bs2;
            float alpha = expf(ah);
            float beta  = expf(bh);
            float nk    = kap + expf(kh - 3.9f);
            a_s[lane]  = alpha;
            nb_s[lane] = -beta;
            nk_s[lane] = nk;
            nk_keep    = nk;
            // term_k(u) = exp(ah - beta*(nk-u)^2) < e^-60 beyond this u:
            cut = nk + sqrtf((60.f + fmaxf(ah, 0.f)) / beta);
        }
        #pragma unroll
        for (int off = 8; off > 0; off >>= 1)
            cut = fmaxf(cut, __shfl_xor(cut, off));
        if (lane == 0) {
            int uc = (int)cut + 1;
            ucut_sh = uc > U_SZ ? U_SZ : uc;
        }
    }
    __syncthreads();  // B: a_s/nb_s/nk_s/ucut_sh + cs ready (LDS-only drain)

    const int ucut = ucut_sh;
    float* pt = out + OUT_PT_OFF + (size_t)b * (U_SZ + 1);

    // phase 3a: phi(u) for u = tid <= ucut; store to LDS, keep s in reg
    float s_head = 0.f;
    if (tid <= ucut) {
        const float fu = (float)tid;
        float s = 0.f;
        #pragma unroll
        for (int k = 0; k < K_SZ; ++k) {
            float d = nk_s[k] - fu;
            s += a_s[k] * expf(nb_s[k] * d * d);
        }
        s_head = s;
        if (tid < len && tid < CPRE) phi_s[tid] = s;
    }
    // pathological fallback (ucut >= 1024; never with this data): direct store
    for (int u = tid + 1024; u <= ucut; u += 1024) {
        const float fu = (float)u;
        float s2 = 0.f;
        #pragma unroll
        for (int k = 0; k < K_SZ; ++k) {
            float d = nk_s[k] - fu;
            s2 += a_s[k] * expf(nb_s[k] * d * d);
        }
        pt[u] = s2;
    }

    __syncthreads();  // D: phi_s ready (LDS-only drain in the normal case)

    // phase 4: w[b,v] partials from LDS (phi_s exactly 0 beyond ulim)
    const int ulim = min(min(len, ucut + 1), U_SZ);
    if (tid < 12 * V_SZ) {
        const int v = tid % V_SZ;
        const int r = tid / V_SZ;
        float acc = 0.f;
        #pragma unroll
        for (int j = 0; j < 6; ++j) {
            const int u = r + 12 * j;
            if (u < CPRE) acc += phi_s[u] * cs[u * V_SZ + v];
        }
        if (ulim > CPRE) {  // cold tail: recompute phi inline, c from global
            int u0 = r + ((CPRE - r + 11) / 12) * 12;
            for (int u = u0; u < ulim; u += 12) {
                const float fu = (float)u;
                float s2 = 0.f;
                #pragma unroll
                for (int k = 0; k < K_SZ; ++k) {
                    float d = nk_s[k] - fu;
                    s2 += a_s[k] * expf(nb_s[k] * d * d);
                }
                acc += s2 * cb[(size_t)u * V_SZ + v];
            }
        }
        wpart[r][v] = acc;
    }
    __syncthreads();  // E (LDS-only drain)

    // ---- post-E: every global store, never drained by any barrier ----

    // w
    if (tid < V_SZ) {
        float s = 0.f;
        #pragma unroll
        for (int r = 0; r < 12; ++r) s += wpart[r][tid];
        out[OUT_W_OFF + b * V_SZ + tid] = s;
    }

    // new_kappa (wave 0 lanes 0-9 still hold it in registers)
    if (wave == 0 && lane < K_SZ)
        out[OUT_NK_OFF + b * K_SZ + lane] = nk_keep;

    // pt head [0..ucut]
    if (tid <= ucut) pt[tid] = s_head;

    // deferred bulk zero-fill pt[(ucut, U]]; nontemporal to keep L2 clean.
    // 4 x 1024 threads cover up to ucut+4096 >= U_SZ for any ucut >= 0.
    #pragma unroll
    for (int j = 0; j < 4; ++j) {
        int uz = ucut + 1 + tid + 1024 * j;
        if (uz <= U_SZ) __builtin_nontemporal_store(0.f, &pt[uz]);
    }
}

extern "C" void kernel_launch(void* const* d_in, const int* in_sizes, int n_in,
                              void* d_out, int out_size, void* d_ws, size_t ws_size,
                              hipStream_t stream) {
    const float* x     = (const float*)d_in[0];
    const float* c     = (const float*)d_in[1];
    const float* kappa = (const float*)d_in[2];
    const float* W     = (const float*)d_in[3];
    const float* bias  = (const float*)d_in[4];
    const int*   lens  = (const int*)d_in[5];
    float* out = (float*)d_out;

    fused_softwindow<<<B_SZ, 1024, 0, stream>>>(x, c, kappa, W, bias, lens, out);
}

// Round 10
// 11.400 us; speedup vs baseline: 1.5706x; 1.5706x over previous
//
#include <hip/hip_runtime.h>
#include <math.h>

#define B_SZ 256
#define U_SZ 4096
#define V_SZ 80
#define H_SZ 1024
#define K_SZ 10
#define CPRE 64                     // c rows staged in LDS (slice A)
#define CPRE_F4 (CPRE * V_SZ / 4)   // 1280 float4
#define NTHR 512

// d_out layout (floats, concatenated in return order):
//   [0, B*V)                       w            (256*80   = 20480)
//   [B*V, B*V + B*K)               new_kappa    (256*10   = 2560)
//   [B*V + B*K, ... + B*(U+1))     phi_term     (256*4097 = 1048832)
#define OUT_W_OFF      0
#define OUT_NK_OFF     (B_SZ * V_SZ)
#define OUT_PT_OFF     (B_SZ * V_SZ + B_SZ * K_SZ)

// Grid = 512: two 512-thread blocks per batch, >=2 blocks/CU co-resident.
// Both slices compute lin -> scalars -> ucut identically (deterministic,
// bitwise-equal), so the pt[] write split  A:[0,ucut]  B:(ucut,U]  is
// disjoint and race-free.
//   Slice A: c rows -> regs -> LDS; lin; scalars+nk; phi head -> pt + LDS;
//            w partials from LDS; reduce + store w.      (R6-proven chain)
//   Slice B: lin; cut only; stream-zero pt[(ucut,U]] (4 MB, nontemporal) —
//            starts right after its lin phase, overlapping slice A's chain.
__global__ __launch_bounds__(NTHR) void fused_softwindow(
        const float* __restrict__ x,
        const float* __restrict__ c,
        const float* __restrict__ kappa,
        const float* __restrict__ W,
        const float* __restrict__ bias,
        const int*   __restrict__ lens,
        float* __restrict__ out) {
    __shared__ float cs[CPRE * V_SZ];          // 20 KB (slice A only)
    __shared__ float lin_s[32];
    __shared__ float a_s[K_SZ], nb_s[K_SZ], nk_s[K_SZ];
    __shared__ float phi_s[128];
    __shared__ float wpart[6][V_SZ];
    __shared__ int   ucut_sh;

    const int  bid  = blockIdx.x;
    const int  b    = bid >> 1;
    const bool isB  = (bid & 1) != 0;          // block-uniform
    const int  tid  = threadIdx.x;
    const int  wave = tid >> 6;
    const int  lane = tid & 63;
    const int  len  = lens[b];

    const float*  cb  = c + (size_t)b * U_SZ * V_SZ;
    const float4* cb4 = (const float4*)cb;

    // ---- entry: independent loads, all drain at barrier A ----
    float4 creg0, creg1, creg2;
    if (!isB) {
        creg0 = cb4[tid];
        creg1 = cb4[tid + NTHR];
        if (tid < CPRE_F4 - 2 * NTHR) creg2 = cb4[tid + 2 * NTHR];
        if (tid < 128) phi_s[tid] = 0.f;
    }

    float kap = 0.f, bs0 = 0.f, bs1 = 0.f, bs2 = 0.f;
    if (tid < K_SZ) {
        kap = kappa[b * K_SZ + tid];
        bs0 = bias[tid];
        bs1 = bias[K_SZ + tid];
        bs2 = bias[2 * K_SZ + tid];
    }

    // lin = x @ W.T  (8 waves cover 30 rows; float4 direct from global)
    {
        const float4* xb4 = (const float4*)(x + (size_t)b * H_SZ);
        float4 xv[4];
        #pragma unroll
        for (int j = 0; j < 4; ++j) xv[j] = xb4[lane + 64 * j];
        for (int k = wave; k < 3 * K_SZ; k += 8) {
            const float4* Wk4 = (const float4*)(W + (size_t)k * H_SZ);
            float p = 0.f;
            #pragma unroll
            for (int j = 0; j < 4; ++j) {
                float4 wv = Wk4[lane + 64 * j];
                p += wv.x * xv[j].x + wv.y * xv[j].y +
                     wv.z * xv[j].z + wv.w * xv[j].w;
            }
            #pragma unroll
            for (int off = 32; off > 0; off >>= 1) p += __shfl_down(p, off);
            if (lane == 0) lin_s[k] = p;
        }
    }

    __syncthreads();  // A: lin_s ready; entry loads drained

    // slice A: creg -> LDS bounce (read in phase 4 after barrier D)
    if (!isB) {
        float4* cs4 = (float4*)cs;
        cs4[tid] = creg0;
        cs4[tid + NTHR] = creg1;
        if (tid < CPRE_F4 - 2 * NTHR) cs4[tid + 2 * NTHR] = creg2;
    }

    // wave-0: scalars + analytic cutoff (terms beyond cut are < e^-60)
    if (wave == 0) {
        float cut = 0.f;
        if (lane < K_SZ) {
            float ah = lin_s[lane]            + bs0;
            float bh = lin_s[K_SZ + lane]     + bs1;
            float kh = lin_s[2 * K_SZ + lane] + bs2;
            float beta = expf(bh);
            float nk   = kap + expf(kh - 3.9f);
            cut = nk + sqrtf((60.f + fmaxf(ah, 0.f)) / beta);
            if (!isB) {
                a_s[lane]  = expf(ah);
                nb_s[lane] = -beta;
                nk_s[lane] = nk;
                out[OUT_NK_OFF + b * K_SZ + lane] = nk;
            }
        }
        #pragma unroll
        for (int off = 8; off > 0; off >>= 1)
            cut = fmaxf(cut, __shfl_xor(cut, off));
        if (lane == 0) {
            int uc = (int)cut + 1;
            ucut_sh = uc > U_SZ ? U_SZ : uc;
        }
    }
    __syncthreads();  // B: ucut (+ slice A: a_s/nb_s/nk_s, cs) ready

    const int ucut = ucut_sh;
    float* pt = out + OUT_PT_OFF + (size_t)b * (U_SZ + 1);

    if (isB) {
        // slice B: stream-zero pt[(ucut, U]] and exit (8 NT stores/thread)
        for (int u = ucut + 1 + tid; u <= U_SZ; u += NTHR)
            __builtin_nontemporal_store(0.f, &pt[u]);
        return;
    }

    // ---- slice A continues (block-uniform path; barriers are per-block) --

    // phase 3a: phi(u) for u <= ucut -> pt + phi_s (normally 1 iteration)
    for (int u = tid; u <= ucut; u += NTHR) {
        const float fu = (float)u;
        float s = 0.f;
        #pragma unroll
        for (int k = 0; k < K_SZ; ++k) {
            float d = nk_s[k] - fu;
            s += a_s[k] * expf(nb_s[k] * d * d);
        }
        pt[u] = s;
        if (u < len && u < 128) phi_s[u] = s;
    }
    __syncthreads();  // D: phi_s ready

    // phase 4: w[b,v] partials (phi_s exactly 0 beyond ulim)
    const int ulim = min(min(len, ucut + 1), U_SZ);
    if (tid < 6 * V_SZ) {
        const int v = tid % V_SZ;
        const int r = tid / V_SZ;
        float acc = 0.f;
        #pragma unroll
        for (int j = 0; j < 11; ++j) {
            const int u = r + 6 * j;
            if (u < CPRE) acc += phi_s[u] * cs[u * V_SZ + v];
        }
        if (ulim > CPRE) {  // cold tail: recompute phi inline, c from global
            int u0 = r + ((CPRE - r + 5) / 6) * 6;
            for (int u = u0; u < ulim; u += 6) {
                const float fu = (float)u;
                float s2 = 0.f;
                #pragma unroll
                for (int k = 0; k < K_SZ; ++k) {
                    float d = nk_s[k] - fu;
                    s2 += a_s[k] * expf(nb_s[k] * d * d);
                }
                acc += s2 * cb[(size_t)u * V_SZ + v];
            }
        }
        wpart[r][v] = acc;
    }
    __syncthreads();  // E

    if (tid < V_SZ) {
        float s = 0.f;
        #pragma unroll
        for (int r = 0; r < 6; ++r) s += wpart[r][tid];
        out[OUT_W_OFF + b * V_SZ + tid] = s;
    }
}

extern "C" void kernel_launch(void* const* d_in, const int* in_sizes, int n_in,
                              void* d_out, int out_size, void* d_ws, size_t ws_size,
                              hipStream_t stream) {
    const float* x     = (const float*)d_in[0];
    const float* c     = (const float*)d_in[1];
    const float* kappa = (const float*)d_in[2];
    const float* W     = (const float*)d_in[3];
    const float* bias  = (const float*)d_in[4];
    const int*   lens  = (const int*)d_in[5];
    float* out = (float*)d_out;

    fused_softwindow<<<2 * B_SZ, NTHR, 0, stream>>>(x, c, kappa, W, bias, lens, out);
}

// Round 11
// 10.720 us; speedup vs baseline: 1.6703x; 1.0635x over previous
//
#include <hip/hip_runtime.h>
#include <math.h>

#define B_SZ 256
#define U_SZ 4096
#define V_SZ 80
#define H_SZ 1024
#define K_SZ 10
#define CPRE 48                     // c rows staged in LDS (covers ucut<=47; tail fallback beyond)
#define CPRE_F4 (CPRE * V_SZ / 4)   // 960 float4

// d_out layout (floats, concatenated in return order):
//   [0, B*V)                       w            (256*80   = 20480)
//   [B*V, B*V + B*K)               new_kappa    (256*10   = 2560)
//   [B*V + B*K, ... + B*(U+1))     phi_term     (256*4097 = 1048832)
#define OUT_W_OFF      0
#define OUT_NK_OFF     (B_SZ * V_SZ)
#define OUT_PT_OFF     (B_SZ * V_SZ + B_SZ * K_SZ)

// One block (1024 threads = 16 waves) per batch. Barrier chain A-B-D-E;
// the 4 MB phi_term zero-fill is DEFERRED to after the last barrier so no
// barrier ever drains it (it retires at kernel end, streaming full-BW).
//   entry:  c rows (960 float4 = 15 KB) -> registers, kappa/bias prefetch,
//           zero phi_s[48] (one conditional LDS store)
//   pre-A:  lin = x @ W.T (x direct from global, L1-cached)
//   A ----  (drain of entry loads; lin_s ready)
//   creg -> LDS ; wave-0 scalars + analytic cutoff (terms beyond < e^-60)
//   B ----
//   phase 3: exp-compute pt[0..ucut] + phi_s
//   D ----
//   phase 4: w partials from LDS c rows (+ rare global tail)
//   E ----  (LDS-only)
//   reduce+store w ; deferred zero-fill pt[(ucut,U]] (nontemporal)
__global__ __launch_bounds__(1024) void fused_softwindow(
        const float* __restrict__ x,
        const float* __restrict__ c,
        const float* __restrict__ kappa,
        const float* __restrict__ W,
        const float* __restrict__ bias,
        const int*   __restrict__ lens,
        float* __restrict__ out) {
    __shared__ float cs[CPRE * V_SZ];          // 15 KB
    __shared__ float lin_s[32];
    __shared__ float a_s[K_SZ], nb_s[K_SZ], nk_s[K_SZ];
    __shared__ float phi_s[CPRE];              // 48 floats
    __shared__ float wpart[12][V_SZ];
    __shared__ int   ucut_sh;

    const int b    = blockIdx.x;
    const int tid  = threadIdx.x;
    const int wave = tid >> 6;
    const int lane = tid & 63;
    const int len  = lens[b];

    const float*  cb  = c + (size_t)b * U_SZ * V_SZ;
    const float4* cb4 = (const float4*)cb;

    // entry: c prefetch into registers — exactly CPRE_F4 = 960 float4
    float4 creg0;
    if (tid < CPRE_F4) creg0 = cb4[tid];

    // entry: kappa/bias prefetch (used by wave 0 in phase 2)
    float kap = 0.f, bs0 = 0.f, bs1 = 0.f, bs2 = 0.f;
    if (tid < K_SZ) {
        kap = kappa[b * K_SZ + tid];
        bs0 = bias[tid];
        bs1 = bias[K_SZ + tid];
        bs2 = bias[2 * K_SZ + tid];
    }

    // zero phi_s (48 entries; cross-thread reads only after barrier D)
    if (tid < CPRE) phi_s[tid] = 0.f;

    // phase 1: lin = x @ W.T, x and W direct from global
    {
        const float4* xb4 = (const float4*)(x + (size_t)b * H_SZ);
        float4 xv[4];
        #pragma unroll
        for (int j = 0; j < 4; ++j) xv[j] = xb4[lane + 64 * j];
        for (int k = wave; k < 3 * K_SZ; k += 16) {
            const float4* Wk4 = (const float4*)(W + (size_t)k * H_SZ);
            float p = 0.f;
            #pragma unroll
            for (int j = 0; j < 4; ++j) {
                float4 wv = Wk4[lane + 64 * j];
                p += wv.x * xv[j].x + wv.y * xv[j].y +
                     wv.z * xv[j].z + wv.w * xv[j].w;
            }
            #pragma unroll
            for (int off = 32; off > 0; off >>= 1) p += __shfl_down(p, off);
            if (lane == 0) lin_s[k] = p;
        }
    }

    __syncthreads();  // A: lin_s ready; entry loads drained

    // creg -> LDS layout bounce (visible to phase 4 after barrier D)
    if (tid < CPRE_F4) {
        float4* cs4 = (float4*)cs;
        cs4[tid] = creg0;
    }

    // phase 2: per-k scalars + in-wave cutoff reduce (wave 0 only)
    if (wave == 0) {
        float cut = 0.f;
        if (lane < K_SZ) {
            float ah = lin_s[lane]            + bs0;
            float bh = lin_s[K_SZ + lane]     + bs1;
            float kh = lin_s[2 * K_SZ + lane] + bs2;
            float alpha = expf(ah);
            float beta  = expf(bh);
            float nk    = kap + expf(kh - 3.9f);
            a_s[lane]  = alpha;
            nb_s[lane] = -beta;
            nk_s[lane] = nk;
            // term_k(u) = exp(ah - beta*(nk-u)^2) < e^-60 beyond this u:
            cut = nk + sqrtf((60.f + fmaxf(ah, 0.f)) / beta);
            out[OUT_NK_OFF + b * K_SZ + lane] = nk;
        }
        #pragma unroll
        for (int off = 8; off > 0; off >>= 1)
            cut = fmaxf(cut, __shfl_xor(cut, off));
        if (lane == 0) {
            int uc = (int)cut + 1;
            ucut_sh = uc > U_SZ ? U_SZ : uc;
        }
    }
    __syncthreads();  // B: a_s/nb_s/nk_s/ucut_sh + cs ready

    const int ucut = ucut_sh;
    float* pt = out + OUT_PT_OFF + (size_t)b * (U_SZ + 1);

    // phase 3a: compute region u in [0, ucut] (normally one iteration)
    for (int u = tid; u <= ucut; u += 1024) {
        const float fu = (float)u;
        float s = 0.f;
        #pragma unroll
        for (int k = 0; k < K_SZ; ++k) {
            float d = nk_s[k] - fu;
            s += a_s[k] * expf(nb_s[k] * d * d);
        }
        pt[u] = s;
        if (u < len && u < CPRE) phi_s[u] = s;
    }

    __syncthreads();  // D: phi_s ready

    // phase 4: w[b,v] (phi_s is exactly 0 beyond ulim)
    const int ulim = min(min(len, ucut + 1), U_SZ);
    if (tid < 12 * V_SZ) {
        const int v = tid % V_SZ;
        const int r = tid / V_SZ;
        float acc = 0.f;
        #pragma unroll
        for (int j = 0; j < 4; ++j) {          // r + 12*3 <= 47 < CPRE
            const int u = r + 12 * j;
            acc += phi_s[u] * cs[u * V_SZ + v];
        }
        if (ulim > CPRE) {  // rare tail: rows not prefetched (still exact)
            int u0 = r + ((CPRE - r + 11) / 12) * 12;
            for (int u = u0; u < ulim; u += 12) {
                const float fu = (float)u;
                float s2 = 0.f;
                #pragma unroll
                for (int k = 0; k < K_SZ; ++k) {
                    float d = nk_s[k] - fu;
                    s2 += a_s[k] * expf(nb_s[k] * d * d);
                }
                acc += s2 * cb[(size_t)u * V_SZ + v];
            }
        }
        wpart[r][v] = acc;
    }
    __syncthreads();  // E

    if (tid < V_SZ) {
        float s = 0.f;
        #pragma unroll
        for (int r = 0; r < 12; ++r) s += wpart[r][tid];
        out[OUT_W_OFF + b * V_SZ + tid] = s;
    }

    // deferred bulk zero-fill pt[(ucut, U]] — after the last barrier, so no
    // barrier drains these 4 MB of streaming stores; nontemporal keeps L2.
    #pragma unroll
    for (int j = 0; j < 4; ++j) {
        int uz = ucut + 1 + tid + 1024 * j;
        if (uz <= U_SZ) __builtin_nontemporal_store(0.f, &pt[uz]);
    }
}

extern "C" void kernel_launch(void* const* d_in, const int* in_sizes, int n_in,
                              void* d_out, int out_size, void* d_ws, size_t ws_size,
                              hipStream_t stream) {
    const float* x     = (const float*)d_in[0];
    const float* c     = (const float*)d_in[1];
    const float* kappa = (const float*)d_in[2];
    const float* W     = (const float*)d_in[3];
    const float* bias  = (const float*)d_in[4];
    const int*   lens  = (const int*)d_in[5];
    float* out = (float*)d_out;

    fused_softwindow<<<B_SZ, 1024, 0, stream>>>(x, c, kappa, W, bias, lens, out);
}